// Round 14
// baseline (1741.106 us; speedup 1.0000x reference)
//
#include <hip/hip_runtime.h>

#define T_STEPS 512
#define F_IN    64
#define HID     20
#define NCLS    10
#define BATCH   1024

typedef __attribute__((ext_vector_type(8))) short bf16x8;   // MFMA A/B operand
typedef __attribute__((ext_vector_type(4))) float f32x4;    // MFMA C/D operand
typedef __attribute__((ext_vector_type(2))) float f32x2;

__device__ __forceinline__ float rcpf(float x) { return __builtin_amdgcn_rcpf(x); }
__device__ __forceinline__ float bperm(int idxBytes, float v) {
    return __int_as_float(__builtin_amdgcn_ds_bpermute(idxBytes, __float_as_int(v)));
}
__device__ __forceinline__ unsigned short bf16h(float v) {  // fp32 -> bf16 bits, RNE
    unsigned u = __float_as_uint(v);
    return (unsigned short)((u + 0x7fffu + ((u >> 16) & 1u)) >> 16);
}
__device__ __forceinline__ float bf16f(unsigned short h) {  // bf16 bits -> fp32
    return __uint_as_float(((unsigned)h) << 16);
}
// packed fp32 FMA (the 157 TF fp32 path)
__device__ __forceinline__ f32x2 pkfma(f32x2 a, f32x2 b, f32x2 c) {
    f32x2 d;
    asm("v_pk_fma_f32 %0, %1, %2, %3" : "=v"(d) : "v"(a), "v"(b), "v"(c));
    return d;
}

// ---------------- kernel A: Z0 = x @ W_ih0^T + b0, split-bf16 MFMA (R8, unchanged) ----------------
extern "C" __global__ __launch_bounds__(256, 2)
void zgemm_mfma(const float* __restrict__ x, const float* __restrict__ W,
                const float* __restrict__ b0, float* __restrict__ Z)
{
    __shared__ unsigned short xlds[4][2][32][72];   // [wave][plane][row][k], 36 KB

    const int tid = threadIdx.x;
    const int w   = tid >> 6;
    const int l   = tid & 63;
    const int ar  = l & 15;
    const int aq  = l >> 4;
    const size_t R0 = ((size_t)blockIdx.x * 4 + w) * 32;

    const float* xw = x + R0 * F_IN;
    #pragma unroll
    for (int i = 0; i < 8; ++i) {
        const int idx = (i << 6) + l;
        const int row = idx >> 4;
        const int c4  = idx & 15;
        const float4 v = *(const float4*)(xw + (row << 6) + (c4 << 2));
        const unsigned short h0 = bf16h(v.x), h1 = bf16h(v.y),
                             h2 = bf16h(v.z), h3 = bf16h(v.w);
        const unsigned short g0 = bf16h(v.x - bf16f(h0)), g1 = bf16h(v.y - bf16f(h1)),
                             g2 = bf16h(v.z - bf16f(h2)), g3 = bf16h(v.w - bf16f(h3));
        *(uint2*)&xlds[w][0][row][c4 << 2] =
            make_uint2((unsigned)h0 | ((unsigned)h1 << 16), (unsigned)h2 | ((unsigned)h3 << 16));
        *(uint2*)&xlds[w][1][row][c4 << 2] =
            make_uint2((unsigned)g0 | ((unsigned)g1 << 16), (unsigned)g2 | ((unsigned)g3 << 16));
    }
    __syncthreads();

    bf16x8 af[2][2][2];
    #pragma unroll
    for (int m = 0; m < 2; ++m)
        #pragma unroll
        for (int s = 0; s < 2; ++s) {
            af[m][s][0] = *(const bf16x8*)&xlds[w][0][m * 16 + ar][aq * 8 + s * 32];
            af[m][s][1] = *(const bf16x8*)&xlds[w][1][m * 16 + ar][aq * 8 + s * 32];
        }

    bf16x8 bfr[5][2][2];
    #pragma unroll
    for (int n = 0; n < 5; ++n)
        #pragma unroll
        for (int s = 0; s < 2; ++s) {
            const float* wp = W + (size_t)(n * 16 + ar) * F_IN + aq * 8 + s * 32;
            const float4 u = *(const float4*)wp;
            const float4 v = *(const float4*)(wp + 4);
            bf16x8 hf, gf;
            hf[0] = (short)bf16h(u.x); gf[0] = (short)bf16h(u.x - bf16f(bf16h(u.x)));
            hf[1] = (short)bf16h(u.y); gf[1] = (short)bf16h(u.y - bf16f(bf16h(u.y)));
            hf[2] = (short)bf16h(u.z); gf[2] = (short)bf16h(u.z - bf16f(bf16h(u.z)));
            hf[3] = (short)bf16h(u.w); gf[3] = (short)bf16h(u.w - bf16f(bf16h(u.w)));
            hf[4] = (short)bf16h(v.x); gf[4] = (short)bf16h(v.x - bf16f(bf16h(v.x)));
            hf[5] = (short)bf16h(v.y); gf[5] = (short)bf16h(v.y - bf16f(bf16h(v.y)));
            hf[6] = (short)bf16h(v.z); gf[6] = (short)bf16h(v.z - bf16f(bf16h(v.z)));
            hf[7] = (short)bf16h(v.w); gf[7] = (short)bf16h(v.w - bf16f(bf16h(v.w)));
            bfr[n][s][0] = hf;
            bfr[n][s][1] = gf;
        }

    #pragma unroll
    for (int m = 0; m < 2; ++m)
        #pragma unroll
        for (int n = 0; n < 5; ++n) {
            const float bb = b0[n * 16 + ar];
            f32x4 acc = {bb, bb, bb, bb};
            #pragma unroll
            for (int s = 0; s < 2; ++s) {
                acc = __builtin_amdgcn_mfma_f32_16x16x32_bf16(af[m][s][0], bfr[n][s][0], acc, 0, 0, 0);
                acc = __builtin_amdgcn_mfma_f32_16x16x32_bf16(af[m][s][0], bfr[n][s][1], acc, 0, 0, 0);
                acc = __builtin_amdgcn_mfma_f32_16x16x32_bf16(af[m][s][1], bfr[n][s][0], acc, 0, 0, 0);
            }
            float* zp = Z + (R0 + m * 16 + aq * 4) * 80 + n * 16 + ar;
            zp[0]   = acc[0];
            zp[80]  = acc[1];
            zp[160] = acc[2];
            zp[240] = acc[3];
        }
}

// ---------------- kernel B: 3-wave layer-pipelined recurrence ----------------
// wave0: layer0(t).  wave1: layer1(t-4).  wave2: FC(t-8) + W_fc streaming (lean).
// Barrier (lgkm-only) every 4 steps. Ring slot disjointness per interval (mod 8):
//   wave0 writes h0 {t..t+3}, wave1 reads h0 {t-4..t-1}  (disjoint)
//   wave1 writes h1 {t-4..t-1}, wave2 reads h1 {t-8..t-5} (disjoint)
// Grid 1024 x 192 -> 3 waves/SIMD.
extern "C" __global__ __launch_bounds__(192, 3)
void lstm_rec(const float* __restrict__ Z0,
              const float* __restrict__ W_hh0,
              const float* __restrict__ W_ih1, const float* __restrict__ W_hh1,
              const float* __restrict__ b1,
              const float* __restrict__ W_fc, const float* __restrict__ b_fc,
              float* __restrict__ out)
{
    __shared__ float4 ringH0v[8][6];     // [slot][24 floats]
    __shared__ float4 ringH1v[8][6];
    float* ringH0 = (float*)ringH0v;
    float* ringH1 = (float*)ringH1v;

    const int tid = threadIdx.x;
    const int l   = tid & 63;
    const int wid = tid >> 6;            // 0:L0  1:L1  2:FC
    const int b   = blockIdx.x;
    const int g2  = 64 + (l & 15);       // secondary gate = o[4..19]
    const bool isG = (l >= 40 && l < 60);

    const float mnegP = isG ? -2.885390082f : -1.442695041f;
    const float sclP  = isG ? 2.0f : 1.0f;
    const float biaP  = isG ? -1.0f : 0.0f;

    const int idxF  = ((l + 20) & 63) << 2;
    const int idxG  = ((l + 40) & 63) << 2;
    const int idxO  = ((l + 60) & 63) << 2;
    const int idxOB = ((l -  4) & 63) << 2;

    for (int i = tid; i < 192; i += 192) { ringH0[i] = 0.f; ringH1[i] = 0.f; }

    // ---------------- wave-0 state ----------------
    f32x2 wh0p2[10], wh0s2[10];
    float c0 = 0.f;
    float zpc = 0.f, zsc = 0.f, zpn = 0.f, zsn = 0.f;
    unsigned zP = 0, zS = 0;
    const char* Zb = (const char*)Z0;
    #define ZLD(o) (*(const float*)(Zb + (o)))

    // ---------------- wave-1 state ----------------
    f32x2 wi1p2[10], wi1s2[10], wh1p2[10], wh1s2[10];
    float b1p = 0.f, b1s = 0.f;
    float c1 = 0.f;

    // ---------------- wave-2 state (lean) ----------------
    f32x2 facc2 = {0.f, 0.f};
    float4 wfc = make_float4(0.f, 0.f, 0.f, 0.f);
    unsigned wfOff = 0;
    int c4off = 0;
    const char* Wfb = (const char*)W_fc;

    if (wid == 0) {
        const f32x2* wp;
        wp = (const f32x2*)(W_hh0 + l  * HID);
        #pragma unroll
        for (int k = 0; k < 10; ++k) wh0p2[k] = wp[k];
        wp = (const f32x2*)(W_hh0 + g2 * HID);
        #pragma unroll
        for (int k = 0; k < 10; ++k) wh0s2[k] = wp[k];

        zP = (unsigned)((b * (T_STEPS * 80) + l) * 4);
        zS = (unsigned)((b * (T_STEPS * 80) + 64 + (l & 15)) * 4);
        zpc = ZLD(zP);       zsc = ZLD(zS);
        zpn = ZLD(zP + 320); zsn = ZLD(zS + 320);
        zP += 640; zS += 640;
    } else if (wid == 1) {
        const f32x2* wp;
        wp = (const f32x2*)(W_ih1 + l  * HID);
        #pragma unroll
        for (int k = 0; k < 10; ++k) wi1p2[k] = wp[k];
        wp = (const f32x2*)(W_ih1 + g2 * HID);
        #pragma unroll
        for (int k = 0; k < 10; ++k) wi1s2[k] = wp[k];
        wp = (const f32x2*)(W_hh1 + l  * HID);
        #pragma unroll
        for (int k = 0; k < 10; ++k) wh1p2[k] = wp[k];
        wp = (const f32x2*)(W_hh1 + g2 * HID);
        #pragma unroll
        for (int k = 0; k < 10; ++k) wh1s2[k] = wp[k];
        b1p = b1[l];
        b1s = b1[g2];
    } else {
        const int cls = (l < 50) ? (l / 5) : 0;
        const int c4  = (l < 50) ? (l % 5) : 0;
        c4off = c4 * 16;
        wfOff = (unsigned)((cls * (T_STEPS * HID) + c4 * 4) * 4);
    }
    __syncthreads();

    #pragma unroll 8
    for (int t = 0; t < T_STEPS + 8; ++t) {
        if (wid == 0) {
            if (t < T_STEPS) {
                const float zp = zpc, zs = zsc;
                zpc = zpn; zsc = zsn;
                if (t + 2 < T_STEPS) {
                    zpn = ZLD(zP); zsn = ZLD(zS);
                    zP += 320; zS += 320;
                }
                // h0(t-1): 5 uniform ds_read_b128
                f32x2 h2[10];
                {
                    const f32x4* hp = (const f32x4*)(ringH0 + ((t + 7) & 7) * 24);
                    #pragma unroll
                    for (int k = 0; k < 5; ++k) {
                        const f32x4 v = hp[k];
                        h2[2 * k]     = __builtin_shufflevector(v, v, 0, 1);
                        h2[2 * k + 1] = __builtin_shufflevector(v, v, 2, 3);
                    }
                }
                f32x2 aP = {zp, 0.f}, aP1 = {0.f, 0.f};
                f32x2 aS = {zs, 0.f}, aS1 = {0.f, 0.f};
                #pragma unroll
                for (int j = 0; j < 5; ++j) {
                    aP  = pkfma(h2[j],     wh0p2[j],     aP);
                    aP1 = pkfma(h2[5 + j], wh0p2[5 + j], aP1);
                    aS  = pkfma(h2[j],     wh0s2[j],     aS);
                    aS1 = pkfma(h2[5 + j], wh0s2[5 + j], aS1);
                }
                const float a_p = (aP.x + aP1.x) + (aP.y + aP1.y);
                const float a_s = (aS.x + aS1.x) + (aS.y + aS1.y);
                const float actP = fmaf(rcpf(1.f + exp2f(a_p * mnegP)), sclP, biaP);
                const float actS = rcpf(1.f + exp2f(a_s * -1.442695041f));
                const float fv = bperm(idxF, actP), gv = bperm(idxG, actP);
                const float oA = bperm(idxO, actP), oB = bperm(idxOB, actS);
                const float ov = (l < 4) ? oA : oB;
                c0 = fmaf(fv, c0, actP * gv);
                const float h0v = ov * fmaf(rcpf(1.f + exp2f(c0 * -2.885390082f)), 2.f, -1.f);
                if (l < HID) ringH0[(t & 7) * 24 + l] = h0v;
            }
        } else if (wid == 1) {
            const int tau = t - 4;                      // layer1 step
            if (tau >= 0 && tau < T_STEPS) {
                f32x2 h02[10], h12[10];
                {
                    const f32x4* hp = (const f32x4*)(ringH0 + (tau & 7) * 24);
                    const f32x4* hq = (const f32x4*)(ringH1 + ((tau + 7) & 7) * 24);
                    #pragma unroll
                    for (int k = 0; k < 5; ++k) {
                        const f32x4 v = hp[k];
                        const f32x4 u = hq[k];
                        h02[2 * k]     = __builtin_shufflevector(v, v, 0, 1);
                        h02[2 * k + 1] = __builtin_shufflevector(v, v, 2, 3);
                        h12[2 * k]     = __builtin_shufflevector(u, u, 0, 1);
                        h12[2 * k + 1] = __builtin_shufflevector(u, u, 2, 3);
                    }
                }
                f32x2 bP = {b1p, 0.f}, bP1 = {0.f, 0.f};
                f32x2 bS = {b1s, 0.f}, bS1 = {0.f, 0.f};
                #pragma unroll
                for (int j = 0; j < 5; ++j) {
                    bP  = pkfma(h12[j],     wh1p2[j],     bP);
                    bP1 = pkfma(h12[5 + j], wh1p2[5 + j], bP1);
                    bS  = pkfma(h12[j],     wh1s2[j],     bS);
                    bS1 = pkfma(h12[5 + j], wh1s2[5 + j], bS1);
                }
                #pragma unroll
                for (int j = 0; j < 5; ++j) {
                    bP  = pkfma(h02[j],     wi1p2[j],     bP);
                    bP1 = pkfma(h02[5 + j], wi1p2[5 + j], bP1);
                    bS  = pkfma(h02[j],     wi1s2[j],     bS);
                    bS1 = pkfma(h02[5 + j], wi1s2[5 + j], bS1);
                }
                const float b_p = (bP.x + bP1.x) + (bP.y + bP1.y);
                const float b_s = (bS.x + bS1.x) + (bS.y + bS1.y);
                const float actQ = fmaf(rcpf(1.f + exp2f(b_p * mnegP)), sclP, biaP);
                const float actT = rcpf(1.f + exp2f(b_s * -1.442695041f));
                const float fv = bperm(idxF, actQ), gv = bperm(idxG, actQ);
                const float oA = bperm(idxO, actQ), oB = bperm(idxOB, actT);
                const float ov = (l < 4) ? oA : oB;
                c1 = fmaf(fv, c1, actQ * gv);
                const float h1v = ov * fmaf(rcpf(1.f + exp2f(c1 * -2.885390082f)), 2.f, -1.f);
                if (l < HID) ringH1[(tau & 7) * 24 + l] = h1v;
            }
        } else {
            const int sigma = t - 8;                    // FC step
            // prefetch wf for next step's FC (sigma_next = t-7), one full step early
            float4 wfn = make_float4(0.f, 0.f, 0.f, 0.f);
            if (t >= 7 && t < T_STEPS + 7) {
                wfn = *(const float4*)(Wfb + wfOff);
                wfOff += HID * 4;
            }
            if (sigma >= 0) {
                const float4 h1q = *(const float4*)((const char*)ringH1 +
                                                    ((sigma & 7) * 96) + c4off);
                facc2 = pkfma((f32x2){h1q.x, h1q.y}, (f32x2){wfc.x, wfc.y}, facc2);
                facc2 = pkfma((f32x2){h1q.z, h1q.w}, (f32x2){wfc.z, wfc.w}, facc2);
            }
            wfc = wfn;
        }
        if ((t & 3) == 3) {
            // LDS-only drain + raw barrier (global prefetches stay in flight)
            asm volatile("s_waitcnt lgkmcnt(0)" ::: "memory");
            __builtin_amdgcn_s_barrier();
            asm volatile("" ::: "memory");
        }
    }

    // ---- epilogue: wave2 reduces FC partials (5 chunk lanes per class) ----
    if (wid == 2) {
        const float f = facc2.x + facc2.y;
        float r = f;
        r += __shfl(f, l + 1);
        r += __shfl(f, l + 2);
        r += __shfl(f, l + 3);
        r += __shfl(f, l + 4);
        if (l < 50 && (l % 5) == 0)
            out[(size_t)b * NCLS + (l / 5)] = r + b_fc[l / 5];
    }
}

extern "C" void kernel_launch(void* const* d_in, const int* in_sizes, int n_in,
                              void* d_out, int out_size, void* d_ws, size_t ws_size,
                              hipStream_t stream) {
    const float* x     = (const float*)d_in[0];
    const float* W_ih0 = (const float*)d_in[1];
    const float* W_hh0 = (const float*)d_in[2];
    const float* b0    = (const float*)d_in[3];
    const float* W_ih1 = (const float*)d_in[4];
    const float* W_hh1 = (const float*)d_in[5];
    const float* b1    = (const float*)d_in[6];
    const float* W_fc  = (const float*)d_in[7];
    const float* b_fc  = (const float*)d_in[8];
    float* out = (float*)d_out;

    float* Z0 = (float*)d_ws;   // B*T*80*4 = 167.8 MB workspace

    zgemm_mfma<<<dim3(4096), dim3(256), 0, stream>>>(x, W_ih0, b0, Z0);
    lstm_rec<<<dim3(BATCH), dim3(192), 0, stream>>>(Z0, W_hh0, W_ih1, W_hh1,
                                                    b1, W_fc, b_fc, out);
}

// Round 15
// 339.155 us; speedup vs baseline: 5.1337x; 5.1337x over previous
//
#include <hip/hip_runtime.h>

#define T_STEPS 512
#define F_IN    64
#define HID     20
#define NCLS    10
#define BATCH   1024

typedef __attribute__((ext_vector_type(8))) short bf16x8;   // MFMA A/B operand
typedef __attribute__((ext_vector_type(4))) float f32x4;    // MFMA C/D operand
typedef __attribute__((ext_vector_type(2))) float f32x2;

__device__ __forceinline__ float rcpf(float x) { return __builtin_amdgcn_rcpf(x); }
__device__ __forceinline__ float bperm(int idxBytes, float v) {
    return __int_as_float(__builtin_amdgcn_ds_bpermute(idxBytes, __float_as_int(v)));
}
__device__ __forceinline__ unsigned short bf16h(float v) {  // fp32 -> bf16 bits, RNE
    unsigned u = __float_as_uint(v);
    return (unsigned short)((u + 0x7fffu + ((u >> 16) & 1u)) >> 16);
}
__device__ __forceinline__ float bf16f(unsigned short h) {  // bf16 bits -> fp32
    return __uint_as_float(((unsigned)h) << 16);
}
// packed fp32 FMA (the 157 TF fp32 path)
__device__ __forceinline__ f32x2 pkfma(f32x2 a, f32x2 b, f32x2 c) {
    f32x2 d;
    asm("v_pk_fma_f32 %0, %1, %2, %3" : "=v"(d) : "v"(a), "v"(b), "v"(c));
    return d;
}

// ---------------- kernel A: Z0 = x @ W_ih0^T + b0, split-bf16 MFMA (R8, unchanged) ----------------
extern "C" __global__ __launch_bounds__(256, 2)
void zgemm_mfma(const float* __restrict__ x, const float* __restrict__ W,
                const float* __restrict__ b0, float* __restrict__ Z)
{
    __shared__ unsigned short xlds[4][2][32][72];   // [wave][plane][row][k], 36 KB

    const int tid = threadIdx.x;
    const int w   = tid >> 6;
    const int l   = tid & 63;
    const int ar  = l & 15;
    const int aq  = l >> 4;
    const size_t R0 = ((size_t)blockIdx.x * 4 + w) * 32;

    const float* xw = x + R0 * F_IN;
    #pragma unroll
    for (int i = 0; i < 8; ++i) {
        const int idx = (i << 6) + l;
        const int row = idx >> 4;
        const int c4  = idx & 15;
        const float4 v = *(const float4*)(xw + (row << 6) + (c4 << 2));
        const unsigned short h0 = bf16h(v.x), h1 = bf16h(v.y),
                             h2 = bf16h(v.z), h3 = bf16h(v.w);
        const unsigned short g0 = bf16h(v.x - bf16f(h0)), g1 = bf16h(v.y - bf16f(h1)),
                             g2 = bf16h(v.z - bf16f(h2)), g3 = bf16h(v.w - bf16f(h3));
        *(uint2*)&xlds[w][0][row][c4 << 2] =
            make_uint2((unsigned)h0 | ((unsigned)h1 << 16), (unsigned)h2 | ((unsigned)h3 << 16));
        *(uint2*)&xlds[w][1][row][c4 << 2] =
            make_uint2((unsigned)g0 | ((unsigned)g1 << 16), (unsigned)g2 | ((unsigned)g3 << 16));
    }
    __syncthreads();

    bf16x8 af[2][2][2];
    #pragma unroll
    for (int m = 0; m < 2; ++m)
        #pragma unroll
        for (int s = 0; s < 2; ++s) {
            af[m][s][0] = *(const bf16x8*)&xlds[w][0][m * 16 + ar][aq * 8 + s * 32];
            af[m][s][1] = *(const bf16x8*)&xlds[w][1][m * 16 + ar][aq * 8 + s * 32];
        }

    bf16x8 bfr[5][2][2];
    #pragma unroll
    for (int n = 0; n < 5; ++n)
        #pragma unroll
        for (int s = 0; s < 2; ++s) {
            const float* wp = W + (size_t)(n * 16 + ar) * F_IN + aq * 8 + s * 32;
            const float4 u = *(const float4*)wp;
            const float4 v = *(const float4*)(wp + 4);
            bf16x8 hf, gf;
            hf[0] = (short)bf16h(u.x); gf[0] = (short)bf16h(u.x - bf16f(bf16h(u.x)));
            hf[1] = (short)bf16h(u.y); gf[1] = (short)bf16h(u.y - bf16f(bf16h(u.y)));
            hf[2] = (short)bf16h(u.z); gf[2] = (short)bf16h(u.z - bf16f(bf16h(u.z)));
            hf[3] = (short)bf16h(u.w); gf[3] = (short)bf16h(u.w - bf16f(bf16h(u.w)));
            hf[4] = (short)bf16h(v.x); gf[4] = (short)bf16h(v.x - bf16f(bf16h(v.x)));
            hf[5] = (short)bf16h(v.y); gf[5] = (short)bf16h(v.y - bf16f(bf16h(v.y)));
            hf[6] = (short)bf16h(v.z); gf[6] = (short)bf16h(v.z - bf16f(bf16h(v.z)));
            hf[7] = (short)bf16h(v.w); gf[7] = (short)bf16h(v.w - bf16f(bf16h(v.w)));
            bfr[n][s][0] = hf;
            bfr[n][s][1] = gf;
        }

    #pragma unroll
    for (int m = 0; m < 2; ++m)
        #pragma unroll
        for (int n = 0; n < 5; ++n) {
            const float bb = b0[n * 16 + ar];
            f32x4 acc = {bb, bb, bb, bb};
            #pragma unroll
            for (int s = 0; s < 2; ++s) {
                acc = __builtin_amdgcn_mfma_f32_16x16x32_bf16(af[m][s][0], bfr[n][s][0], acc, 0, 0, 0);
                acc = __builtin_amdgcn_mfma_f32_16x16x32_bf16(af[m][s][0], bfr[n][s][1], acc, 0, 0, 0);
                acc = __builtin_amdgcn_mfma_f32_16x16x32_bf16(af[m][s][1], bfr[n][s][0], acc, 0, 0, 0);
            }
            float* zp = Z + (R0 + m * 16 + aq * 4) * 80 + n * 16 + ar;
            zp[0]   = acc[0];
            zp[80]  = acc[1];
            zp[160] = acc[2];
            zp[240] = acc[3];
        }
}

// ---------------- kernel B: R9 layer-pipelined recurrence, barrier every 4 steps ----------------
// block = 1 elem, 2 waves. wave0: layer0(t) + FC(t-8). wave1: layer1(t-4).
// 8-slot rings; per-4-step-interval slot disjointness:
//   ringH0: wave0 writes {t..t+3}&7, wave1 reads {t-4..t-1}&7  (disjoint)
//   ringH1: wave1 writes {t-4..t-1}&7, FC reads {t-8..t-5}&7   (disjoint; write in
//           interval k-1, read in k, overwrite in k+1 -> 1 barrier between each)
// Barrier = lgkmcnt(0)-only + raw s_barrier (global prefetches stay in flight).
extern "C" __global__ __launch_bounds__(128, 2)
void lstm_rec(const float* __restrict__ Z0,
              const float* __restrict__ W_hh0,
              const float* __restrict__ W_ih1, const float* __restrict__ W_hh1,
              const float* __restrict__ b1,
              const float* __restrict__ W_fc, const float* __restrict__ b_fc,
              float* __restrict__ out)
{
    __shared__ float4 ringH0v[8][6];     // [slot][24 floats]
    __shared__ float4 ringH1v[8][6];
    float* ringH0 = (float*)ringH0v;
    float* ringH1 = (float*)ringH1v;

    const int tid = threadIdx.x;
    const int l   = tid & 63;
    const int wid = tid >> 6;            // 0 = layer0+FC, 1 = layer1
    const int b   = blockIdx.x;
    const int g2  = 64 + (l & 15);       // secondary gate = o[4..19]
    const bool isG = (l >= 40 && l < 60);

    const float mnegP = isG ? -2.885390082f : -1.442695041f;
    const float sclP  = isG ? 2.0f : 1.0f;
    const float biaP  = isG ? -1.0f : 0.0f;

    const int idxF  = ((l + 20) & 63) << 2;
    const int idxG  = ((l + 40) & 63) << 2;
    const int idxO  = ((l + 60) & 63) << 2;
    const int idxOB = ((l -  4) & 63) << 2;

    for (int i = tid; i < 192; i += 128) { ringH0[i] = 0.f; ringH1[i] = 0.f; }

    // ---------------- wave-0 state ----------------
    f32x2 wh0p2[10], wh0s2[10];
    float c0 = 0.f;
    float zpc = 0.f, zsc = 0.f, zpn = 0.f, zsn = 0.f;
    unsigned zP = 0, zS = 0;
    const char* Zb = (const char*)Z0;
    #define ZLD(o) (*(const float*)(Zb + (o)))
    f32x2 facc2 = {0.f, 0.f};
    float4 wfc = make_float4(0.f, 0.f, 0.f, 0.f);   // wf for sigma = t-8 (prefetched)
    unsigned wfOff = 0;
    int c4off = 0;
    const char* Wfb = (const char*)W_fc;

    // ---------------- wave-1 state ----------------
    f32x2 wi1p2[10], wi1s2[10], wh1p2[10], wh1s2[10];
    float b1p = 0.f, b1s = 0.f;
    float c1 = 0.f;

    if (wid == 0) {
        const f32x2* p;
        p = (const f32x2*)(W_hh0 + l  * HID);
        #pragma unroll
        for (int k = 0; k < 10; ++k) wh0p2[k] = p[k];
        p = (const f32x2*)(W_hh0 + g2 * HID);
        #pragma unroll
        for (int k = 0; k < 10; ++k) wh0s2[k] = p[k];

        zP = (unsigned)((b * (T_STEPS * 80) + l) * 4);
        zS = (unsigned)((b * (T_STEPS * 80) + 64 + (l & 15)) * 4);
        zpc = ZLD(zP);       zsc = ZLD(zS);
        zpn = ZLD(zP + 320); zsn = ZLD(zS + 320);
        zP += 640; zS += 640;

        const int cls = (l < 50) ? (l / 5) : 0;
        const int c4  = (l < 50) ? (l % 5) : 0;
        c4off = c4 * 16;
        wfOff = (unsigned)((cls * (T_STEPS * HID) + c4 * 4) * 4);
    } else {
        const f32x2* p;
        p = (const f32x2*)(W_ih1 + l  * HID);
        #pragma unroll
        for (int k = 0; k < 10; ++k) wi1p2[k] = p[k];
        p = (const f32x2*)(W_ih1 + g2 * HID);
        #pragma unroll
        for (int k = 0; k < 10; ++k) wi1s2[k] = p[k];
        p = (const f32x2*)(W_hh1 + l  * HID);
        #pragma unroll
        for (int k = 0; k < 10; ++k) wh1p2[k] = p[k];
        p = (const f32x2*)(W_hh1 + g2 * HID);
        #pragma unroll
        for (int k = 0; k < 10; ++k) wh1s2[k] = p[k];
        b1p = b1[l];
        b1s = b1[g2];
    }
    __syncthreads();

    #pragma unroll 8
    for (int t = 0; t < T_STEPS + 8; ++t) {
        if (wid == 0) {
            const int sigma = t - 8;                    // FC step
            // prefetch wf for NEXT step's FC (sigma_next = t-7), one full step early
            float4 wfn = make_float4(0.f, 0.f, 0.f, 0.f);
            if (t >= 7 && t < T_STEPS + 7) {
                wfn = *(const float4*)(Wfb + wfOff);
                wfOff += HID * 4;
            }
            if (t < T_STEPS) {
                const float zp = zpc, zs = zsc;
                zpc = zpn; zsc = zsn;
                if (t + 2 < T_STEPS) {
                    zpn = ZLD(zP); zsn = ZLD(zS);
                    zP += 320; zS += 320;
                }
                // h0(t-1): 5 uniform ds_read_b128 (own write, same wave)
                f32x2 h2[10];
                {
                    const f32x4* hp = (const f32x4*)(ringH0 + ((t + 7) & 7) * 24);
                    #pragma unroll
                    for (int k = 0; k < 5; ++k) {
                        const f32x4 v = hp[k];
                        h2[2 * k]     = __builtin_shufflevector(v, v, 0, 1);
                        h2[2 * k + 1] = __builtin_shufflevector(v, v, 2, 3);
                    }
                }
                f32x2 aP = {zp, 0.f}, aP1 = {0.f, 0.f};
                f32x2 aS = {zs, 0.f}, aS1 = {0.f, 0.f};
                #pragma unroll
                for (int j = 0; j < 5; ++j) {
                    aP  = pkfma(h2[j],     wh0p2[j],     aP);
                    aP1 = pkfma(h2[5 + j], wh0p2[5 + j], aP1);
                    aS  = pkfma(h2[j],     wh0s2[j],     aS);
                    aS1 = pkfma(h2[5 + j], wh0s2[5 + j], aS1);
                }
                const float a_p = (aP.x + aP1.x) + (aP.y + aP1.y);
                const float a_s = (aS.x + aS1.x) + (aS.y + aS1.y);
                const float actP = fmaf(rcpf(1.f + exp2f(a_p * mnegP)), sclP, biaP);
                const float actS = rcpf(1.f + exp2f(a_s * -1.442695041f));
                const float fv = bperm(idxF, actP), gv = bperm(idxG, actP);
                const float oA = bperm(idxO, actP), oB = bperm(idxOB, actS);
                const float ov = (l < 4) ? oA : oB;
                c0 = fmaf(fv, c0, actP * gv);
                const float h0v = ov * fmaf(rcpf(1.f + exp2f(c0 * -2.885390082f)), 2.f, -1.f);
                if (l < HID) ringH0[(t & 7) * 24 + l] = h0v;
            }
            if (sigma >= 0) {
                const float4 h1q = *(const float4*)((const char*)ringH1 +
                                                    ((sigma & 7) * 96) + c4off);
                facc2 = pkfma((f32x2){h1q.x, h1q.y}, (f32x2){wfc.x, wfc.y}, facc2);
                facc2 = pkfma((f32x2){h1q.z, h1q.w}, (f32x2){wfc.z, wfc.w}, facc2);
            }
            wfc = wfn;
        } else {
            const int tau = t - 4;                      // layer1 step
            if (tau >= 0 && tau < T_STEPS) {
                f32x2 h02[10], h12[10];
                {
                    const f32x4* hp = (const f32x4*)(ringH0 + (tau & 7) * 24);
                    const f32x4* hq = (const f32x4*)(ringH1 + ((tau + 7) & 7) * 24);
                    #pragma unroll
                    for (int k = 0; k < 5; ++k) {
                        const f32x4 v = hp[k];
                        const f32x4 u = hq[k];
                        h02[2 * k]     = __builtin_shufflevector(v, v, 0, 1);
                        h02[2 * k + 1] = __builtin_shufflevector(v, v, 2, 3);
                        h12[2 * k]     = __builtin_shufflevector(u, u, 0, 1);
                        h12[2 * k + 1] = __builtin_shufflevector(u, u, 2, 3);
                    }
                }
                f32x2 bP = {b1p, 0.f}, bP1 = {0.f, 0.f};
                f32x2 bS = {b1s, 0.f}, bS1 = {0.f, 0.f};
                #pragma unroll
                for (int j = 0; j < 5; ++j) {
                    bP  = pkfma(h12[j],     wh1p2[j],     bP);
                    bP1 = pkfma(h12[5 + j], wh1p2[5 + j], bP1);
                    bS  = pkfma(h12[j],     wh1s2[j],     bS);
                    bS1 = pkfma(h12[5 + j], wh1s2[5 + j], bS1);
                }
                #pragma unroll
                for (int j = 0; j < 5; ++j) {
                    bP  = pkfma(h02[j],     wi1p2[j],     bP);
                    bP1 = pkfma(h02[5 + j], wi1p2[5 + j], bP1);
                    bS  = pkfma(h02[j],     wi1s2[j],     bS);
                    bS1 = pkfma(h02[5 + j], wi1s2[5 + j], bS1);
                }
                const float b_p = (bP.x + bP1.x) + (bP.y + bP1.y);
                const float b_s = (bS.x + bS1.x) + (bS.y + bS1.y);
                const float actQ = fmaf(rcpf(1.f + exp2f(b_p * mnegP)), sclP, biaP);
                const float actT = rcpf(1.f + exp2f(b_s * -1.442695041f));
                const float fv = bperm(idxF, actQ), gv = bperm(idxG, actQ);
                const float oA = bperm(idxO, actQ), oB = bperm(idxOB, actT);
                const float ov = (l < 4) ? oA : oB;
                c1 = fmaf(fv, c1, actQ * gv);
                const float h1v = ov * fmaf(rcpf(1.f + exp2f(c1 * -2.885390082f)), 2.f, -1.f);
                if (l < HID) ringH1[(tau & 7) * 24 + l] = h1v;
            }
        }
        if ((t & 3) == 3) {
            // LDS-only drain + raw barrier: global prefetches stay in flight
            asm volatile("s_waitcnt lgkmcnt(0)" ::: "memory");
            __builtin_amdgcn_s_barrier();
            asm volatile("" ::: "memory");
        }
    }

    // epilogue: wave0 reduces FC partials (5 chunk-lanes per class)
    if (wid == 0) {
        const float f = facc2.x + facc2.y;
        float r = f;
        r += __shfl(f, l + 1);
        r += __shfl(f, l + 2);
        r += __shfl(f, l + 3);
        r += __shfl(f, l + 4);
        if (l < 50 && (l % 5) == 0)
            out[(size_t)b * NCLS + (l / 5)] = r + b_fc[l / 5];
    }
}

extern "C" void kernel_launch(void* const* d_in, const int* in_sizes, int n_in,
                              void* d_out, int out_size, void* d_ws, size_t ws_size,
                              hipStream_t stream) {
    const float* x     = (const float*)d_in[0];
    const float* W_ih0 = (const float*)d_in[1];
    const float* W_hh0 = (const float*)d_in[2];
    const float* b0    = (const float*)d_in[3];
    const float* W_ih1 = (const float*)d_in[4];
    const float* W_hh1 = (const float*)d_in[5];
    const float* b1    = (const float*)d_in[6];
    const float* W_fc  = (const float*)d_in[7];
    const float* b_fc  = (const float*)d_in[8];
    float* out = (float*)d_out;

    float* Z0 = (float*)d_ws;   // B*T*80*4 = 167.8 MB workspace

    zgemm_mfma<<<dim3(4096), dim3(256), 0, stream>>>(x, W_ih0, b0, Z0);
    lstm_rec<<<dim3(BATCH), dim3(128), 0, stream>>>(Z0, W_hh0, W_ih1, W_hh1,
                                                    b1, W_fc, b_fc, out);
}

// Round 16
// 318.577 us; speedup vs baseline: 5.4653x; 1.0646x over previous
//
#include <hip/hip_runtime.h>

#define T_STEPS 512
#define F_IN    64
#define HID     20
#define NCLS    10
#define BATCH   1024

typedef __attribute__((ext_vector_type(8))) short bf16x8;   // MFMA A/B operand
typedef __attribute__((ext_vector_type(4))) float f32x4;    // MFMA C/D operand
typedef __attribute__((ext_vector_type(2))) float f32x2;

__device__ __forceinline__ float rcpf(float x) { return __builtin_amdgcn_rcpf(x); }
__device__ __forceinline__ float bperm(int idxBytes, float v) {
    return __int_as_float(__builtin_amdgcn_ds_bpermute(idxBytes, __float_as_int(v)));
}
__device__ __forceinline__ unsigned short bf16h(float v) {  // fp32 -> bf16 bits, RNE
    unsigned u = __float_as_uint(v);
    return (unsigned short)((u + 0x7fffu + ((u >> 16) & 1u)) >> 16);
}
__device__ __forceinline__ float bf16f(unsigned short h) {  // bf16 bits -> fp32
    return __uint_as_float(((unsigned)h) << 16);
}
// packed fp32 FMA (the 157 TF fp32 path)
__device__ __forceinline__ f32x2 pkfma(f32x2 a, f32x2 b, f32x2 c) {
    f32x2 d;
    asm("v_pk_fma_f32 %0, %1, %2, %3" : "=v"(d) : "v"(a), "v"(b), "v"(c));
    return d;
}

// ---------------- kernel A: Z0 = x @ W_ih0^T + b0, split-bf16 MFMA ----------------
extern "C" __global__ __launch_bounds__(256, 2)
void zgemm_mfma(const float* __restrict__ x, const float* __restrict__ W,
                const float* __restrict__ b0, float* __restrict__ Z)
{
    __shared__ unsigned short xlds[4][2][32][72];   // [wave][plane][row][k], 36 KB

    const int tid = threadIdx.x;
    const int w   = tid >> 6;
    const int l   = tid & 63;
    const int ar  = l & 15;
    const int aq  = l >> 4;
    const size_t R0 = ((size_t)blockIdx.x * 4 + w) * 32;

    const float* xw = x + R0 * F_IN;
    #pragma unroll
    for (int i = 0; i < 8; ++i) {
        const int idx = (i << 6) + l;
        const int row = idx >> 4;
        const int c4  = idx & 15;
        const float4 v = *(const float4*)(xw + (row << 6) + (c4 << 2));
        const unsigned short h0 = bf16h(v.x), h1 = bf16h(v.y),
                             h2 = bf16h(v.z), h3 = bf16h(v.w);
        const unsigned short g0 = bf16h(v.x - bf16f(h0)), g1 = bf16h(v.y - bf16f(h1)),
                             g2 = bf16h(v.z - bf16f(h2)), g3 = bf16h(v.w - bf16f(h3));
        *(uint2*)&xlds[w][0][row][c4 << 2] =
            make_uint2((unsigned)h0 | ((unsigned)h1 << 16), (unsigned)h2 | ((unsigned)h3 << 16));
        *(uint2*)&xlds[w][1][row][c4 << 2] =
            make_uint2((unsigned)g0 | ((unsigned)g1 << 16), (unsigned)g2 | ((unsigned)g3 << 16));
    }
    __syncthreads();

    bf16x8 af[2][2][2];
    #pragma unroll
    for (int m = 0; m < 2; ++m)
        #pragma unroll
        for (int s = 0; s < 2; ++s) {
            af[m][s][0] = *(const bf16x8*)&xlds[w][0][m * 16 + ar][aq * 8 + s * 32];
            af[m][s][1] = *(const bf16x8*)&xlds[w][1][m * 16 + ar][aq * 8 + s * 32];
        }

    bf16x8 bfr[5][2][2];
    #pragma unroll
    for (int n = 0; n < 5; ++n)
        #pragma unroll
        for (int s = 0; s < 2; ++s) {
            const float* wp = W + (size_t)(n * 16 + ar) * F_IN + aq * 8 + s * 32;
            const float4 u = *(const float4*)wp;
            const float4 v = *(const float4*)(wp + 4);
            bf16x8 hf, gf;
            hf[0] = (short)bf16h(u.x); gf[0] = (short)bf16h(u.x - bf16f(bf16h(u.x)));
            hf[1] = (short)bf16h(u.y); gf[1] = (short)bf16h(u.y - bf16f(bf16h(u.y)));
            hf[2] = (short)bf16h(u.z); gf[2] = (short)bf16h(u.z - bf16f(bf16h(u.z)));
            hf[3] = (short)bf16h(u.w); gf[3] = (short)bf16h(u.w - bf16f(bf16h(u.w)));
            hf[4] = (short)bf16h(v.x); gf[4] = (short)bf16h(v.x - bf16f(bf16h(v.x)));
            hf[5] = (short)bf16h(v.y); gf[5] = (short)bf16h(v.y - bf16f(bf16h(v.y)));
            hf[6] = (short)bf16h(v.z); gf[6] = (short)bf16h(v.z - bf16f(bf16h(v.z)));
            hf[7] = (short)bf16h(v.w); gf[7] = (short)bf16h(v.w - bf16f(bf16h(v.w)));
            bfr[n][s][0] = hf;
            bfr[n][s][1] = gf;
        }

    #pragma unroll
    for (int m = 0; m < 2; ++m)
        #pragma unroll
        for (int n = 0; n < 5; ++n) {
            const float bb = b0[n * 16 + ar];
            f32x4 acc = {bb, bb, bb, bb};
            #pragma unroll
            for (int s = 0; s < 2; ++s) {
                acc = __builtin_amdgcn_mfma_f32_16x16x32_bf16(af[m][s][0], bfr[n][s][0], acc, 0, 0, 0);
                acc = __builtin_amdgcn_mfma_f32_16x16x32_bf16(af[m][s][0], bfr[n][s][1], acc, 0, 0, 0);
                acc = __builtin_amdgcn_mfma_f32_16x16x32_bf16(af[m][s][1], bfr[n][s][0], acc, 0, 0, 0);
            }
            float* zp = Z + (R0 + m * 16 + aq * 4) * 80 + n * 16 + ar;
            zp[0]   = acc[0];
            zp[80]  = acc[1];
            zp[160] = acc[2];
            zp[240] = acc[3];
        }
}

// ---------------- kernel B: layer-pipelined recurrence (R9 champion) ----------------
// block = 1 elem, 2 waves. wave0: layer0(t) + FC(t-4). wave1: layer1(t-2).
// Barrier = lgkmcnt(0)-only + raw s_barrier every 2 steps: global prefetches (z, wf)
// stay in flight across barriers. wf prefetched one full step ahead.
extern "C" __global__ __launch_bounds__(128, 2)
void lstm_rec(const float* __restrict__ Z0,
              const float* __restrict__ W_hh0,
              const float* __restrict__ W_ih1, const float* __restrict__ W_hh1,
              const float* __restrict__ b1,
              const float* __restrict__ W_fc, const float* __restrict__ b_fc,
              float* __restrict__ out)
{
    __shared__ float4 ringH0v[4][6];     // [slot][24 floats]
    __shared__ float4 ringH1v[8][6];
    float* ringH0 = (float*)ringH0v;
    float* ringH1 = (float*)ringH1v;

    const int tid = threadIdx.x;
    const int l   = tid & 63;
    const int wid = tid >> 6;            // 0 = layer0+FC, 1 = layer1
    const int b   = blockIdx.x;
    const int g2  = 64 + (l & 15);       // secondary gate = o[4..19]
    const bool isG = (l >= 40 && l < 60);

    const float mnegP = isG ? -2.885390082f : -1.442695041f;
    const float sclP  = isG ? 2.0f : 1.0f;
    const float biaP  = isG ? -1.0f : 0.0f;

    const int idxF  = ((l + 20) & 63) << 2;
    const int idxG  = ((l + 40) & 63) << 2;
    const int idxO  = ((l + 60) & 63) << 2;
    const int idxOB = ((l -  4) & 63) << 2;

    for (int i = tid; i < 96; i += 128)  ringH0[i] = 0.f;
    for (int i = tid; i < 192; i += 128) ringH1[i] = 0.f;

    // ---------------- wave-0 state ----------------
    f32x2 wh0p2[10], wh0s2[10];
    float c0 = 0.f;
    float zpc = 0.f, zsc = 0.f, zpn = 0.f, zsn = 0.f;
    unsigned zP = 0, zS = 0;
    const char* Zb = (const char*)Z0;
    #define ZLD(o) (*(const float*)(Zb + (o)))
    f32x2 facc2 = {0.f, 0.f};
    float4 wfc = make_float4(0.f, 0.f, 0.f, 0.f);   // wf for sigma = t-4 (prefetched)
    unsigned wfOff = 0;
    int c4off = 0;
    const char* Wfb = (const char*)W_fc;

    // ---------------- wave-1 state ----------------
    f32x2 wi1p2[10], wi1s2[10], wh1p2[10], wh1s2[10];
    float b1p = 0.f, b1s = 0.f;
    float c1 = 0.f;

    if (wid == 0) {
        const f32x2* p;
        p = (const f32x2*)(W_hh0 + l  * HID);
        #pragma unroll
        for (int k = 0; k < 10; ++k) wh0p2[k] = p[k];
        p = (const f32x2*)(W_hh0 + g2 * HID);
        #pragma unroll
        for (int k = 0; k < 10; ++k) wh0s2[k] = p[k];

        zP = (unsigned)((b * (T_STEPS * 80) + l) * 4);
        zS = (unsigned)((b * (T_STEPS * 80) + 64 + (l & 15)) * 4);
        zpc = ZLD(zP);       zsc = ZLD(zS);
        zpn = ZLD(zP + 320); zsn = ZLD(zS + 320);
        zP += 640; zS += 640;

        const int cls = (l < 50) ? (l / 5) : 0;
        const int c4  = (l < 50) ? (l % 5) : 0;
        c4off = c4 * 16;
        wfOff = (unsigned)((cls * (T_STEPS * HID) + c4 * 4) * 4);
    } else {
        const f32x2* p;
        p = (const f32x2*)(W_ih1 + l  * HID);
        #pragma unroll
        for (int k = 0; k < 10; ++k) wi1p2[k] = p[k];
        p = (const f32x2*)(W_ih1 + g2 * HID);
        #pragma unroll
        for (int k = 0; k < 10; ++k) wi1s2[k] = p[k];
        p = (const f32x2*)(W_hh1 + l  * HID);
        #pragma unroll
        for (int k = 0; k < 10; ++k) wh1p2[k] = p[k];
        p = (const f32x2*)(W_hh1 + g2 * HID);
        #pragma unroll
        for (int k = 0; k < 10; ++k) wh1s2[k] = p[k];
        b1p = b1[l];
        b1s = b1[g2];
    }
    __syncthreads();

    #pragma unroll 8
    for (int t = 0; t < T_STEPS + 4; ++t) {
        if (wid == 0) {
            const int sigma = t - 4;
            // prefetch wf for NEXT step's FC (sigma_next = t-3), one full step early
            float4 wfn = make_float4(0.f, 0.f, 0.f, 0.f);
            if (t >= 3 && t < T_STEPS + 3) {
                wfn = *(const float4*)(Wfb + wfOff);
                wfOff += HID * 4;
            }
            if (t < T_STEPS) {
                const float zp = zpc, zs = zsc;
                zpc = zpn; zsc = zsn;
                if (t + 2 < T_STEPS) {
                    zpn = ZLD(zP); zsn = ZLD(zS);
                    zP += 320; zS += 320;
                }
                // h0(t-1) broadcast: 5 uniform ds_read_b128 -> 10 f32x2
                f32x2 h2[10];
                {
                    const f32x4* hp = (const f32x4*)(ringH0 + ((t + 3) & 3) * 24);
                    #pragma unroll
                    for (int k = 0; k < 5; ++k) {
                        const f32x4 v = hp[k];
                        h2[2 * k]     = __builtin_shufflevector(v, v, 0, 1);
                        h2[2 * k + 1] = __builtin_shufflevector(v, v, 2, 3);
                    }
                }
                f32x2 aP = {zp, 0.f}, aP1 = {0.f, 0.f};
                f32x2 aS = {zs, 0.f}, aS1 = {0.f, 0.f};
                #pragma unroll
                for (int j = 0; j < 5; ++j) {
                    aP  = pkfma(h2[j],     wh0p2[j],     aP);
                    aP1 = pkfma(h2[5 + j], wh0p2[5 + j], aP1);
                    aS  = pkfma(h2[j],     wh0s2[j],     aS);
                    aS1 = pkfma(h2[5 + j], wh0s2[5 + j], aS1);
                }
                const float a_p = (aP.x + aP1.x) + (aP.y + aP1.y);
                const float a_s = (aS.x + aS1.x) + (aS.y + aS1.y);
                const float actP = fmaf(rcpf(1.f + exp2f(a_p * mnegP)), sclP, biaP);
                const float actS = rcpf(1.f + exp2f(a_s * -1.442695041f));
                const float fv = bperm(idxF, actP), gv = bperm(idxG, actP);
                const float oA = bperm(idxO, actP), oB = bperm(idxOB, actS);
                const float ov = (l < 4) ? oA : oB;
                c0 = fmaf(fv, c0, actP * gv);
                const float h0v = ov * fmaf(rcpf(1.f + exp2f(c0 * -2.885390082f)), 2.f, -1.f);
                if (l < HID) ringH0[(t & 3) * 24 + l] = h0v;
            }
            if (sigma >= 0) {
                const float4 h1q = *(const float4*)((const char*)ringH1 +
                                                    ((sigma & 7) * 96) + c4off);
                facc2 = pkfma((f32x2){h1q.x, h1q.y}, (f32x2){wfc.x, wfc.y}, facc2);
                facc2 = pkfma((f32x2){h1q.z, h1q.w}, (f32x2){wfc.z, wfc.w}, facc2);
            }
            wfc = wfn;
        } else {
            const int tau = t - 2;
            if (tau >= 0 && tau < T_STEPS) {
                f32x2 h02[10], h12[10];
                {
                    const f32x4* hp = (const f32x4*)(ringH0 + (tau & 3) * 24);
                    const f32x4* hq = (const f32x4*)(ringH1 + ((tau + 7) & 7) * 24);
                    #pragma unroll
                    for (int k = 0; k < 5; ++k) {
                        const f32x4 v = hp[k];
                        const f32x4 u = hq[k];
                        h02[2 * k]     = __builtin_shufflevector(v, v, 0, 1);
                        h02[2 * k + 1] = __builtin_shufflevector(v, v, 2, 3);
                        h12[2 * k]     = __builtin_shufflevector(u, u, 0, 1);
                        h12[2 * k + 1] = __builtin_shufflevector(u, u, 2, 3);
                    }
                }
                f32x2 bP = {b1p, 0.f}, bP1 = {0.f, 0.f};
                f32x2 bS = {b1s, 0.f}, bS1 = {0.f, 0.f};
                #pragma unroll
                for (int j = 0; j < 5; ++j) {
                    bP  = pkfma(h12[j],     wh1p2[j],     bP);
                    bP1 = pkfma(h12[5 + j], wh1p2[5 + j], bP1);
                    bS  = pkfma(h12[j],     wh1s2[j],     bS);
                    bS1 = pkfma(h12[5 + j], wh1s2[5 + j], bS1);
                }
                #pragma unroll
                for (int j = 0; j < 5; ++j) {
                    bP  = pkfma(h02[j],     wi1p2[j],     bP);
                    bP1 = pkfma(h02[5 + j], wi1p2[5 + j], bP1);
                    bS  = pkfma(h02[j],     wi1s2[j],     bS);
                    bS1 = pkfma(h02[5 + j], wi1s2[5 + j], bS1);
                }
                const float b_p = (bP.x + bP1.x) + (bP.y + bP1.y);
                const float b_s = (bS.x + bS1.x) + (bS.y + bS1.y);
                const float actQ = fmaf(rcpf(1.f + exp2f(b_p * mnegP)), sclP, biaP);
                const float actT = rcpf(1.f + exp2f(b_s * -1.442695041f));
                const float fv = bperm(idxF, actQ), gv = bperm(idxG, actQ);
                const float oA = bperm(idxO, actQ), oB = bperm(idxOB, actT);
                const float ov = (l < 4) ? oA : oB;
                c1 = fmaf(fv, c1, actQ * gv);
                const float h1v = ov * fmaf(rcpf(1.f + exp2f(c1 * -2.885390082f)), 2.f, -1.f);
                if (l < HID) ringH1[(tau & 7) * 24 + l] = h1v;
            }
        }
        if (t & 1) {
            // LDS-only drain + raw barrier: global prefetches stay in flight
            asm volatile("s_waitcnt lgkmcnt(0)" ::: "memory");
            __builtin_amdgcn_s_barrier();
            asm volatile("" ::: "memory");
        }
    }

    if (wid == 0) {
        const float f = facc2.x + facc2.y;
        float r = f;
        r += __shfl(f, l + 1);
        r += __shfl(f, l + 2);
        r += __shfl(f, l + 3);
        r += __shfl(f, l + 4);
        if (l < 50 && (l % 5) == 0)
            out[(size_t)b * NCLS + (l / 5)] = r + b_fc[l / 5];
    }
}

extern "C" void kernel_launch(void* const* d_in, const int* in_sizes, int n_in,
                              void* d_out, int out_size, void* d_ws, size_t ws_size,
                              hipStream_t stream) {
    const float* x     = (const float*)d_in[0];
    const float* W_ih0 = (const float*)d_in[1];
    const float* W_hh0 = (const float*)d_in[2];
    const float* b0    = (const float*)d_in[3];
    const float* W_ih1 = (const float*)d_in[4];
    const float* W_hh1 = (const float*)d_in[5];
    const float* b1    = (const float*)d_in[6];
    const float* W_fc  = (const float*)d_in[7];
    const float* b_fc  = (const float*)d_in[8];
    float* out = (float*)d_out;

    float* Z0 = (float*)d_ws;   // B*T*80*4 = 167.8 MB workspace

    zgemm_mfma<<<dim3(4096), dim3(256), 0, stream>>>(x, W_ih0, b0, Z0);
    lstm_rec<<<dim3(BATCH), dim3(128), 0, stream>>>(Z0, W_hh0, W_ih1, W_hh1,
                                                    b1, W_fc, b_fc, out);
}